// Round 9
// baseline (93.629 us; speedup 1.0000x reference)
//
#include <hip/hip_runtime.h>
#include <float.h>
#include <math.h>

// Problem constants (fixed by reference setup_inputs)
constexpr int NQ = 2048;    // queries
constexpr int ND = 65536;   // data points
constexpr int D  = 16;      // dims

// ---- MFMA-path tiling (R4 config: best measured) ----
constexpr int SCH   = 64;           // point chunks
constexpr int CP    = ND / SCH;     // 1024 points per chunk
constexpr int TPW   = CP / 32;      // 32 point-tiles (32 pts) per wave

typedef short bf16x8 __attribute__((ext_vector_type(8)));
typedef float f32x16 __attribute__((ext_vector_type(16)));

__device__ __forceinline__ unsigned short f2bf(float f) {  // RNE fp32->bf16
    unsigned u = __float_as_uint(f);
    u += 0x7FFFu + ((u >> 16) & 1u);
    return (unsigned short)(u >> 16);
}
__device__ __forceinline__ float bf2f(unsigned short h) {
    return __uint_as_float(((unsigned)h) << 16);
}

// ---------------------------------------------------------------------------
// Pack kernel (data only), MFMA-FRAGMENT-MAJOR layout:
//   Per 32-point tile t (2048 B = 1024 shorts):
//     [hi: lane 0..63 x 8 bf16][lo: lane 0..63 x 8 bf16]
//   where lane l consumes point (t*32 + (l&31)), elems (l>>5)*8 .. +8.
// XCD-SWIZZLED 1-D launch (256 blocks): blocks packing chunk cy run on
// XCD cy%8 (linear id % 8), matching knn_mfma's placement, so the chunk is
// resident in that XCD's L2 when knn_mfma's staging reads it.
// ---------------------------------------------------------------------------
__global__ __launch_bounds__(256) void pack_data(const float* __restrict__ data,
                                                 unsigned short* __restrict__ Ppk,
                                                 float* __restrict__ nhf) {
    // lb = (cy%8) + 8*(q4 + 4*(cy/8));  bijective over 256 blocks.
    const int lb  = blockIdx.x;
    const int xcd = lb & 7;
    const int r   = lb >> 3;       // [0,32)
    const int q4  = r & 3;         // quarter-chunk (256 pts)
    const int cg  = r >> 2;        // [0,8)
    const int cy  = xcd + 8 * cg;  // chunk [0,64)
    const int p   = cy * CP + q4 * 256 + threadIdx.x;

    const float4* r4 = (const float4*)(data + (size_t)p * D);
    float4 a = r4[0], b = r4[1], c = r4[2], e = r4[3];
    float v[16] = {a.x, a.y, a.z, a.w, b.x, b.y, b.z, b.w,
                   c.x, c.y, c.z, c.w, e.x, e.y, e.z, e.w};
    unsigned short hi[16], lo[16];
    float n = 0.f;
#pragma unroll
    for (int k = 0; k < 16; ++k) {
        n = fmaf(v[k], v[k], n);
        unsigned short h = f2bf(v[k]);
        hi[k] = h;
        lo[k] = f2bf(v[k] - bf2f(h));   // exact residual, rounded to bf16
    }
    const int t  = p >> 5;        // tile
    const int cc = p & 31;        // point-in-tile == output column == lane&31
    unsigned short* tb = Ppk + (size_t)t * 1024;
    const uint4* h4 = (const uint4*)hi;
    const uint4* l4 = (const uint4*)lo;
    *(uint4*)(tb +        cc * 8) = h4[0];   // hi, half 0 lane (cc)
    *(uint4*)(tb + 256 +  cc * 8) = h4[1];   // hi, half 1 lane (32+cc)
    *(uint4*)(tb + 512 +  cc * 8) = l4[0];   // lo, half 0
    *(uint4*)(tb + 768 +  cc * 8) = l4[1];   // lo, half 1
    nhf[p] = -0.5f * n;
}

// ---------------------------------------------------------------------------
// Main kernel: per wave, 64 queries (2 q-sets of 32) x one 1024-point chunk.
//   best[q] = max_p ( x_q . p - 0.5*||p||^2 )   (argmin dist2 == argmax this)
// R8 structure (LDS staging) + ROUND 9 FIX: the main pair loop is now FULLY
// UNROLLED. In R8 the loop index p was runtime, so nv[p]/nv[p+1] forced the
// nv[32] array into SCRATCH (private HBM) — 32 scratch stores + 32 scratch
// loads per thread of ~500-cyc latency in the hot loop (skill rule #20),
// which re-introduced exactly the latency-exposure the LDS staging had
// removed (knn_mfma stuck at ~22 us vs ~6 us static floor). Full unroll
// makes every nv index a literal -> nv lives in VGPRs, and the scheduler
// can pipeline ds_reads across pairs with counted lgkmcnt.
// Staging: block stages its 64 KiB chunk ONCE (16 coalesced uint4
// load->ds_write_b128 iterations), one __syncthreads, then the MFMA loop
// reads ONLY LDS. LDS = exactly 64 KiB -> 2 blocks/CU.
// XCD-SWIZZLED 1-D launch (512 blocks): all 8 q-slice blocks of chunk cy on
// XCD cy%8 so staging reads hit the L2 lines pack_data wrote.
// Per 32-pt tile per q-set: 3x mfma_f32_32x32x16_bf16 (hi*hi + lo*hi +
// hi*lo), C seeded with -0.5*||p||^2; 4 independent accumulator chains;
// per-pair epilogue 16x v_max3_f32 per q-set.
// C/D: col = lane&31, row = (reg&3) + 8*(reg>>2) + 4*(lane>>5)  [m74/m101].
// ---------------------------------------------------------------------------
__global__ __launch_bounds__(256, 2) void knn_mfma(const float* __restrict__ x,
                                                   const unsigned short* __restrict__ Ppk,
                                                   const float* __restrict__ nhf,
                                                   float* __restrict__ part) {
    // lb = (cy%8) + 8*(qx + 8*(cy/8));  bijective over 512 blocks.
    const int lb  = blockIdx.x;
    const int xcd = lb & 7;
    const int rr  = lb >> 3;       // [0,64)
    const int qx  = rr & 7;        // q-slice [0,8)
    const int cg  = rr >> 3;       // [0,8)
    const int cy  = xcd + 8 * cg;  // chunk [0,64)

    const int tid  = threadIdx.x;
    const int w    = tid >> 6;
    const int l    = tid & 63;
    const int half = l >> 5;
    const int n31  = l & 31;
    const int qbase = qx * 256 + w * 64;   // 4 waves x 64 queries
    const int pbase = cy * CP;

    __shared__ __align__(16) unsigned short sP[32768];  // exactly 64 KiB

    // ---- stage chunk into LDS: 16 coalesced copies (4 KiB/iter/block) ----
    const char* gC = (const char*)Ppk + (size_t)cy * 65536;  // chunk base
    char*       lC = (char*)sP;
#pragma unroll
    for (int i = 0; i < 16; ++i) {
        const int off = i * 4096 + tid * 16;
        uint4 v = *(const uint4*)(gC + off);
        *(uint4*)(lC + off) = v;
    }

    // ---- hoist all 32 per-tile norms into registers (one load burst) ----
    const float* np = nhf + pbase + n31;
    float nv[32];
#pragma unroll
    for (int t = 0; t < 32; ++t) nv[t] = np[t * 32];

    // ---- A fragments (hi/lo bf16) for both q-sets ----
    bf16x8 axh0, axl0, axh1, axl1;
    {
        const float* xr0 = x + (size_t)(qbase + n31) * D + half * 8;
        float4 a0 = *(const float4*)xr0;
        float4 a1 = *(const float4*)(xr0 + 4);
        const float xv0[8] = {a0.x, a0.y, a0.z, a0.w, a1.x, a1.y, a1.z, a1.w};
#pragma unroll
        for (int k = 0; k < 8; ++k) {
            unsigned short h = f2bf(xv0[k]);
            axh0[k] = (short)h;
            axl0[k] = (short)f2bf(xv0[k] - bf2f(h));
        }
        const float* xr1 = x + (size_t)(qbase + 32 + n31) * D + half * 8;
        float4 b0 = *(const float4*)xr1;
        float4 b1 = *(const float4*)(xr1 + 4);
        const float xv1[8] = {b0.x, b0.y, b0.z, b0.w, b1.x, b1.y, b1.z, b1.w};
#pragma unroll
        for (int k = 0; k < 8; ++k) {
            unsigned short h = f2bf(xv1[k]);
            axh1[k] = (short)h;
            axl1[k] = (short)f2bf(xv1[k] - bf2f(h));
        }
    }

    __syncthreads();   // staging writes visible to all waves

    // LDS read pointers: byte layout identical to global fragment-major.
    const unsigned short* lp = sP + l * 8;
#define LDH(t) (*(const bf16x8*)(lp + (size_t)(t) * 1024))
#define LDL(t) (*(const bf16x8*)(lp + (size_t)(t) * 1024 + 512))

    f32x16 rbest0, rbest1;
#pragma unroll
    for (int r = 0; r < 16; ++r) { rbest0[r] = -FLT_MAX; rbest1[r] = -FLT_MAX; }

    auto compute_pair = [&](bf16x8 h0, bf16x8 l0, float n0,
                            bf16x8 h1, bf16x8 l1, float n1) {
        f32x16 c00, c01, c10, c11;   // c[qset][tile]
#pragma unroll
        for (int r = 0; r < 16; ++r) {
            c00[r] = n0; c01[r] = n1; c10[r] = n0; c11[r] = n1;
        }
        // 4 independent accumulator chains, 3 MFMAs deep each.
        c00 = __builtin_amdgcn_mfma_f32_32x32x16_bf16(axh0, h0, c00, 0, 0, 0);
        c01 = __builtin_amdgcn_mfma_f32_32x32x16_bf16(axh0, h1, c01, 0, 0, 0);
        c10 = __builtin_amdgcn_mfma_f32_32x32x16_bf16(axh1, h0, c10, 0, 0, 0);
        c11 = __builtin_amdgcn_mfma_f32_32x32x16_bf16(axh1, h1, c11, 0, 0, 0);
        c00 = __builtin_amdgcn_mfma_f32_32x32x16_bf16(axl0, h0, c00, 0, 0, 0);
        c01 = __builtin_amdgcn_mfma_f32_32x32x16_bf16(axl0, h1, c01, 0, 0, 0);
        c10 = __builtin_amdgcn_mfma_f32_32x32x16_bf16(axl1, h0, c10, 0, 0, 0);
        c11 = __builtin_amdgcn_mfma_f32_32x32x16_bf16(axl1, h1, c11, 0, 0, 0);
        c00 = __builtin_amdgcn_mfma_f32_32x32x16_bf16(axh0, l0, c00, 0, 0, 0);
        c01 = __builtin_amdgcn_mfma_f32_32x32x16_bf16(axh0, l1, c01, 0, 0, 0);
        c10 = __builtin_amdgcn_mfma_f32_32x32x16_bf16(axh1, l0, c10, 0, 0, 0);
        c11 = __builtin_amdgcn_mfma_f32_32x32x16_bf16(axh1, l1, c11, 0, 0, 0);
#pragma unroll
        for (int r = 0; r < 16; ++r) {
            rbest0[r] = fmaxf(rbest0[r], fmaxf(c00[r], c01[r]));  // -> v_max3_f32
            rbest1[r] = fmaxf(rbest1[r], fmaxf(c10[r], c11[r]));
        }
    };

    // FULLY UNROLLED (rule #20): static indices keep nv in VGPRs and let the
    // scheduler pipeline ds_reads across pairs with counted lgkmcnt waits.
#pragma unroll
    for (int p = 0; p < TPW; p += 2) {
        compute_pair(LDH(p),     LDL(p),     nv[p],
                     LDH(p + 1), LDL(p + 1), nv[p + 1]);
    }
#undef LDH
#undef LDL

    // max over the 32 point-columns (lanes within each half)
#pragma unroll
    for (int r = 0; r < 16; ++r) {
        float v0 = rbest0[r];
        v0 = fmaxf(v0, __shfl_xor(v0, 1, 32));
        v0 = fmaxf(v0, __shfl_xor(v0, 2, 32));
        v0 = fmaxf(v0, __shfl_xor(v0, 4, 32));
        v0 = fmaxf(v0, __shfl_xor(v0, 8, 32));
        v0 = fmaxf(v0, __shfl_xor(v0, 16, 32));
        rbest0[r] = v0;
        float v1 = rbest1[r];
        v1 = fmaxf(v1, __shfl_xor(v1, 1, 32));
        v1 = fmaxf(v1, __shfl_xor(v1, 2, 32));
        v1 = fmaxf(v1, __shfl_xor(v1, 4, 32));
        v1 = fmaxf(v1, __shfl_xor(v1, 8, 32));
        v1 = fmaxf(v1, __shfl_xor(v1, 16, 32));
        rbest1[r] = v1;
    }
    if (n31 == 0) {
        float* pp = part + (size_t)cy * NQ + qbase + 4 * half;
#pragma unroll
        for (int r = 0; r < 16; ++r) pp[(r & 3) + 8 * (r >> 2)] = rbest0[r];
        pp += 32;
#pragma unroll
        for (int r = 0; r < 16; ++r) pp[(r & 3) + 8 * (r >> 2)] = rbest1[r];
    }
}

// ---------------------------------------------------------------------------
// Final: reduce SCH chunks, dist2 = ||x||^2 - 2*best, bump.
// ---------------------------------------------------------------------------
__global__ __launch_bounds__(256) void knn_final(const float* __restrict__ x,
                                                 const float* __restrict__ part,
                                                 float* __restrict__ out) {
    const int q = blockIdx.x * 256 + threadIdx.x;
    const float4* xr = (const float4*)(x + (size_t)q * D);
    float4 a = xr[0], b = xr[1], c = xr[2], e = xr[3];
    float x2 = a.x * a.x;
    x2 = fmaf(a.y, a.y, x2); x2 = fmaf(a.z, a.z, x2); x2 = fmaf(a.w, a.w, x2);
    x2 = fmaf(b.x, b.x, x2); x2 = fmaf(b.y, b.y, x2); x2 = fmaf(b.z, b.z, x2); x2 = fmaf(b.w, b.w, x2);
    x2 = fmaf(c.x, c.x, x2); x2 = fmaf(c.y, c.y, x2); x2 = fmaf(c.z, c.z, x2); x2 = fmaf(c.w, c.w, x2);
    x2 = fmaf(e.x, e.x, x2); x2 = fmaf(e.y, e.y, x2); x2 = fmaf(e.z, e.z, x2); x2 = fmaf(e.w, e.w, x2);

    float mbest = -FLT_MAX;
#pragma unroll
    for (int cI = 0; cI < SCH; ++cI) mbest = fmaxf(mbest, part[(size_t)cI * NQ + q]);

    float nn2  = fmaxf(fmaf(-2.f, mbest, x2), 0.f);
    float dist = sqrtf(fmaxf(nn2, 1e-12f));
    float bump = 0.f;
    if (dist < 2.0f) {                      // RADIUS = 2
        float denom = dist * dist - 4.0f;   // d^2 - r^2
        bump = expf(1.0f / denom + 0.25f);  // DECAY/denom + DECAY/r^2
    }
    out[q] = bump;
}

// ===========================================================================
// Fallback (fp32 scalar-pipe path) if workspace is too small for MFMA path.
// ===========================================================================
__global__ __launch_bounds__(256) void neg_half_norms(const float* __restrict__ data,
                                                      float* __restrict__ nhn) {
    const int p = blockIdx.x * 256 + threadIdx.x;
    const float4* r = (const float4*)(data + (size_t)p * D);
    float4 a = r[0], b = r[1], c = r[2], e = r[3];
    float n = a.x * a.x;
    n = fmaf(a.y, a.y, n); n = fmaf(a.z, a.z, n); n = fmaf(a.w, a.w, n);
    n = fmaf(b.x, b.x, n); n = fmaf(b.y, b.y, n); n = fmaf(b.z, b.z, n); n = fmaf(b.w, b.w, n);
    n = fmaf(c.x, c.x, n); n = fmaf(c.y, c.y, n); n = fmaf(c.z, c.z, n); n = fmaf(c.w, c.w, n);
    n = fmaf(e.x, e.x, n); n = fmaf(e.y, e.y, n); n = fmaf(e.z, e.z, n); n = fmaf(e.w, e.w, n);
    nhn[p] = -0.5f * n;
}

__global__ __launch_bounds__(256) void knn_partial_fb(const float* __restrict__ x,
                                                      const float* __restrict__ data,
                                                      const float* __restrict__ nhn,
                                                      float* __restrict__ part, int cp) {
    const int q     = blockIdx.x * 256 + threadIdx.x;
    const int pbase = blockIdx.y * cp;
    const float4* xr = (const float4*)(x + (size_t)q * D);
    const float4 xa = xr[0], xb = xr[1], xc = xr[2], xd = xr[3];
    const float* dp = data + (size_t)pbase * D;
    const float* np = nhn + pbase;
    float best = -FLT_MAX;
    for (int i = 0; i < cp; i += 4) {
#pragma unroll
        for (int j = 0; j < 4; ++j) {
            const float* r  = dp + (size_t)(i + j) * D;
            const float  hn = np[i + j];
            float ca = xa.x * r[0];
            ca = fmaf(xa.y, r[1], ca);  ca = fmaf(xa.z, r[2], ca);  ca = fmaf(xa.w, r[3], ca);
            ca = fmaf(xb.x, r[4], ca);  ca = fmaf(xb.y, r[5], ca);  ca = fmaf(xb.z, r[6], ca);
            ca = fmaf(xb.w, r[7], ca);
            float cb = fmaf(xc.x, r[8], hn);
            cb = fmaf(xc.y, r[9],  cb); cb = fmaf(xc.z, r[10], cb); cb = fmaf(xc.w, r[11], cb);
            cb = fmaf(xd.x, r[12], cb); cb = fmaf(xd.y, r[13], cb); cb = fmaf(xd.z, r[14], cb);
            cb = fmaf(xd.w, r[15], cb);
            best = fmaxf(best, ca + cb);
        }
    }
    part[(size_t)blockIdx.y * NQ + q] = best;
}

__global__ __launch_bounds__(256) void knn_final_fb(const float* __restrict__ x,
                                                    const float* __restrict__ part,
                                                    float* __restrict__ out, int S) {
    const int q = blockIdx.x * 256 + threadIdx.x;
    const float4* xr = (const float4*)(x + (size_t)q * D);
    float4 a = xr[0], b = xr[1], c = xr[2], e = xr[3];
    float x2 = a.x * a.x;
    x2 = fmaf(a.y, a.y, x2); x2 = fmaf(a.z, a.z, x2); x2 = fmaf(a.w, a.w, x2);
    x2 = fmaf(b.x, b.x, x2); x2 = fmaf(b.y, b.y, x2); x2 = fmaf(b.z, b.z, x2); x2 = fmaf(b.w, b.w, x2);
    x2 = fmaf(c.x, c.x, x2); x2 = fmaf(c.y, c.y, x2); x2 = fmaf(c.z, c.z, x2); x2 = fmaf(c.w, c.w, x2);
    x2 = fmaf(e.x, e.x, x2); x2 = fmaf(e.y, e.y, x2); x2 = fmaf(e.z, e.z, x2); x2 = fmaf(e.w, e.w, x2);
    float mb = -FLT_MAX;
    for (int cI = 0; cI < S; ++cI) mb = fmaxf(mb, part[(size_t)cI * NQ + q]);
    float nn2  = fmaxf(fmaf(-2.f, mb, x2), 0.f);
    float dist = sqrtf(fmaxf(nn2, 1e-12f));
    float bump = 0.f;
    if (dist < 2.0f) {
        float denom = dist * dist - 4.0f;
        bump = expf(1.0f / denom + 0.25f);
    }
    out[q] = bump;
}

extern "C" void kernel_launch(void* const* d_in, const int* in_sizes, int n_in,
                              void* d_out, int out_size, void* d_ws, size_t ws_size,
                              hipStream_t stream) {
    const float* x    = (const float*)d_in[0];   // [2048,16] fp32
    const float* data = (const float*)d_in[1];   // [65536,16] fp32
    float* out = (float*)d_out;                  // [2048] fp32

    // ws layout (bytes):
    //   Ppk  [0, 4 MiB)          ND/32 tiles * 1024 shorts (fragment-major)
    //   nhf  [4 MiB, +256 KiB)   ND fp32
    //   part [+512 KiB)          SCH*NQ fp32
    const size_t off_nhf  = (size_t)ND * 32 * 2;             // 4194304
    const size_t off_part = off_nhf + (size_t)ND * 4;        // 4456448
    const size_t needed   = off_part + (size_t)SCH * NQ * 4; // 4980736

    if (ws_size >= needed) {
        unsigned short* Ppk = (unsigned short*)d_ws;
        float* nhf  = (float*)((char*)d_ws + off_nhf);
        float* part = (float*)((char*)d_ws + off_part);

        pack_data<<<ND / 256, 256, 0, stream>>>(data, Ppk, nhf);
        knn_mfma<<<8 * SCH, 256, 0, stream>>>(x, Ppk, nhf, part);
        knn_final<<<NQ / 256, 256, 0, stream>>>(x, part, out);
    } else {
        int S = 32;
        while (S > 1 && (size_t)(ND + S * NQ) * sizeof(float) > ws_size) S >>= 1;
        const int cp = ND / S;
        float* nhn  = (float*)d_ws;
        float* part = (float*)d_ws + ND;
        neg_half_norms<<<ND / 256, 256, 0, stream>>>(data, nhn);
        knn_partial_fb<<<dim3(NQ / 256, S), 256, 0, stream>>>(x, data, nhn, part, cp);
        knn_final_fb<<<NQ / 256, 256, 0, stream>>>(x, part, out, S);
    }
}

// Round 11
// 76.850 us; speedup vs baseline: 1.2183x; 1.2183x over previous
//
#include <hip/hip_runtime.h>
#include <float.h>
#include <math.h>

// Problem constants (fixed by reference setup_inputs)
constexpr int NQ = 2048;    // queries
constexpr int ND = 65536;   // data points
constexpr int D  = 16;      // dims

// ---- MFMA-path tiling (R4 config: best measured) ----
constexpr int SCH   = 64;           // point chunks
constexpr int CP    = ND / SCH;     // 1024 points per chunk
constexpr int TPW   = CP / 32;      // 32 point-tiles (32 pts) per wave

// Dynamic LDS: 64 KiB staged chunk + 4 KiB staged norms (CP=1024 floats!
// R10 bug: staged only 1 KiB = 256 norms -> LDN read garbage for t>=8).
constexpr unsigned LDS_BYTES = 65536 + 4096;

typedef short bf16x8 __attribute__((ext_vector_type(8)));
typedef float f32x16 __attribute__((ext_vector_type(16)));

__device__ __forceinline__ unsigned short f2bf(float f) {  // RNE fp32->bf16
    unsigned u = __float_as_uint(f);
    u += 0x7FFFu + ((u >> 16) & 1u);
    return (unsigned short)(u >> 16);
}
__device__ __forceinline__ float bf2f(unsigned short h) {
    return __uint_as_float(((unsigned)h) << 16);
}

// ---------------------------------------------------------------------------
// Pack kernel (data only), MFMA-FRAGMENT-MAJOR layout:
//   Per 32-point tile t (2048 B = 1024 shorts):
//     [hi: lane 0..63 x 8 bf16][lo: lane 0..63 x 8 bf16]
//   where lane l consumes point (t*32 + (l&31)), elems (l>>5)*8 .. +8.
// XCD-SWIZZLED 1-D launch (256 blocks): blocks packing chunk cy run on
// XCD cy%8 (linear id % 8), matching knn_mfma's placement, so the chunk is
// resident in that XCD's L2 when knn_mfma's staging reads it.
// ---------------------------------------------------------------------------
__global__ __launch_bounds__(256) void pack_data(const float* __restrict__ data,
                                                 unsigned short* __restrict__ Ppk,
                                                 float* __restrict__ nhf) {
    // lb = (cy%8) + 8*(q4 + 4*(cy/8));  bijective over 256 blocks.
    const int lb  = blockIdx.x;
    const int xcd = lb & 7;
    const int r   = lb >> 3;       // [0,32)
    const int q4  = r & 3;         // quarter-chunk (256 pts)
    const int cg  = r >> 2;        // [0,8)
    const int cy  = xcd + 8 * cg;  // chunk [0,64)
    const int p   = cy * CP + q4 * 256 + threadIdx.x;

    const float4* r4 = (const float4*)(data + (size_t)p * D);
    float4 a = r4[0], b = r4[1], c = r4[2], e = r4[3];
    float v[16] = {a.x, a.y, a.z, a.w, b.x, b.y, b.z, b.w,
                   c.x, c.y, c.z, c.w, e.x, e.y, e.z, e.w};
    unsigned short hi[16], lo[16];
    float n = 0.f;
#pragma unroll
    for (int k = 0; k < 16; ++k) {
        n = fmaf(v[k], v[k], n);
        unsigned short h = f2bf(v[k]);
        hi[k] = h;
        lo[k] = f2bf(v[k] - bf2f(h));   // exact residual, rounded to bf16
    }
    const int t  = p >> 5;        // tile
    const int cc = p & 31;        // point-in-tile == output column == lane&31
    unsigned short* tb = Ppk + (size_t)t * 1024;
    const uint4* h4 = (const uint4*)hi;
    const uint4* l4 = (const uint4*)lo;
    *(uint4*)(tb +        cc * 8) = h4[0];   // hi, half 0 lane (cc)
    *(uint4*)(tb + 256 +  cc * 8) = h4[1];   // hi, half 1 lane (32+cc)
    *(uint4*)(tb + 512 +  cc * 8) = l4[0];   // lo, half 0
    *(uint4*)(tb + 768 +  cc * 8) = l4[1];   // lo, half 1
    nhf[p] = -0.5f * n;
}

// ---------------------------------------------------------------------------
// Main kernel: per wave, 64 queries (2 q-sets of 32) x one 1024-point chunk.
//   best[q] = max_p ( x_q . p - 0.5*||p||^2 )   (argmin dist2 == argmax this)
// ROUND 11 = ROUND 10 STRUCTURE + NORM-BUFFER SIZING FIX.
//   - R8: nv[32] register array + runtime loop index -> scratch (rule #20) —
//     staged loop still latency-bound on scratch round-trips.
//   - R9: full unroll -> ds_read hoisting -> VGPR blowout -> worse spill
//     (WRITE_SIZE 68 MB, 45 us, MfmaUtil 0.06%).
//   - R10: norms moved to LDS (correct idea) but staged only 256 of the
//     CP=1024 chunk norms -> LDN(t>=8) read garbage -> absmax 1.0. FIXED:
//     sN = 4 KiB = 1024 floats, staged by all 256 threads (one uint4 each).
// Loop stays ROLLED; norms are runtime-indexed LDS (addressed memory, ~6 cyc
// ds_read_b32) — NO register array with a runtime index remains anywhere.
// LDS = 64 KiB chunk + 4 KiB norms = 69632 B DYNAMIC (static __shared__ caps
// at 64 KiB); 2 blocks/CU (139 KiB / 160 KiB) — occupancy unchanged vs R8.
// Staging: block stages chunk ONCE (16 coalesced uint4 -> ds_write_b128
// iterations, +1 for norms), one __syncthreads, loop reads ONLY LDS.
// XCD-SWIZZLED 1-D launch (512 blocks): all 8 q-slice blocks of chunk cy on
// XCD cy%8 so staging reads hit the L2 lines pack_data wrote.
// Per 32-pt tile per q-set: 3x mfma_f32_32x32x16_bf16 (hi*hi + lo*hi +
// hi*lo), C seeded with -0.5*||p||^2; 4 independent accumulator chains;
// per-pair epilogue 16x v_max3_f32 per q-set.
// C/D: col = lane&31, row = (reg&3) + 8*(reg>>2) + 4*(lane>>5)  [m74/m101].
// ---------------------------------------------------------------------------
__global__ __launch_bounds__(256, 2) void knn_mfma(const float* __restrict__ x,
                                                   const unsigned short* __restrict__ Ppk,
                                                   const float* __restrict__ nhf,
                                                   float* __restrict__ part) {
    // lb = (cy%8) + 8*(qx + 8*(cy/8));  bijective over 512 blocks.
    const int lb  = blockIdx.x;
    const int xcd = lb & 7;
    const int rr  = lb >> 3;       // [0,64)
    const int qx  = rr & 7;        // q-slice [0,8)
    const int cg  = rr >> 3;       // [0,8)
    const int cy  = xcd + 8 * cg;  // chunk [0,64)

    const int tid  = threadIdx.x;
    const int w    = tid >> 6;
    const int l    = tid & 63;
    const int half = l >> 5;
    const int n31  = l & 31;
    const int qbase = qx * 256 + w * 64;   // 4 waves x 64 queries
    const int pbase = cy * CP;

    extern __shared__ __align__(16) char smem[];
    unsigned short* sP = (unsigned short*)smem;          // 64 KiB chunk
    float*          sN = (float*)(smem + 65536);         // 4 KiB: CP norms

    // ---- stage chunk into LDS: 16 coalesced copies (4 KiB/iter/block) ----
    const char* gC = (const char*)Ppk + (size_t)cy * 65536;  // chunk base
    char*       lC = (char*)sP;
#pragma unroll
    for (int i = 0; i < 16; ++i) {
        const int off = i * 4096 + tid * 16;
        uint4 v = *(const uint4*)(gC + off);
        *(uint4*)(lC + off) = v;
    }
    // ---- stage ALL CP=1024 chunk norms (4 KiB): one uint4 per thread ----
    {
        const int off = tid * 16;
        uint4 v = *(const uint4*)((const char*)(nhf + pbase) + off);
        *(uint4*)((char*)sN + off) = v;
    }

    // ---- A fragments (hi/lo bf16) for both q-sets ----
    bf16x8 axh0, axl0, axh1, axl1;
    {
        const float* xr0 = x + (size_t)(qbase + n31) * D + half * 8;
        float4 a0 = *(const float4*)xr0;
        float4 a1 = *(const float4*)(xr0 + 4);
        const float xv0[8] = {a0.x, a0.y, a0.z, a0.w, a1.x, a1.y, a1.z, a1.w};
#pragma unroll
        for (int k = 0; k < 8; ++k) {
            unsigned short h = f2bf(xv0[k]);
            axh0[k] = (short)h;
            axl0[k] = (short)f2bf(xv0[k] - bf2f(h));
        }
        const float* xr1 = x + (size_t)(qbase + 32 + n31) * D + half * 8;
        float4 b0 = *(const float4*)xr1;
        float4 b1 = *(const float4*)(xr1 + 4);
        const float xv1[8] = {b0.x, b0.y, b0.z, b0.w, b1.x, b1.y, b1.z, b1.w};
#pragma unroll
        for (int k = 0; k < 8; ++k) {
            unsigned short h = f2bf(xv1[k]);
            axh1[k] = (short)h;
            axl1[k] = (short)f2bf(xv1[k] - bf2f(h));
        }
    }

    __syncthreads();   // staging writes visible to all waves

    // LDS read pointers: byte layout identical to global fragment-major.
    const unsigned short* lp  = sP + l * 8;
    const float*          lnp = sN + n31;
#define LDH(t) (*(const bf16x8*)(lp + (size_t)(t) * 1024))
#define LDL(t) (*(const bf16x8*)(lp + (size_t)(t) * 1024 + 512))
#define LDN(t) (lnp[(t) * 32])

    f32x16 rbest0, rbest1;
#pragma unroll
    for (int r = 0; r < 16; ++r) { rbest0[r] = -FLT_MAX; rbest1[r] = -FLT_MAX; }

    auto compute_pair = [&](bf16x8 h0, bf16x8 l0, float n0,
                            bf16x8 h1, bf16x8 l1, float n1) {
        f32x16 c00, c01, c10, c11;   // c[qset][tile]
#pragma unroll
        for (int r = 0; r < 16; ++r) {
            c00[r] = n0; c01[r] = n1; c10[r] = n0; c11[r] = n1;
        }
        // 4 independent accumulator chains, 3 MFMAs deep each.
        c00 = __builtin_amdgcn_mfma_f32_32x32x16_bf16(axh0, h0, c00, 0, 0, 0);
        c01 = __builtin_amdgcn_mfma_f32_32x32x16_bf16(axh0, h1, c01, 0, 0, 0);
        c10 = __builtin_amdgcn_mfma_f32_32x32x16_bf16(axh1, h0, c10, 0, 0, 0);
        c11 = __builtin_amdgcn_mfma_f32_32x32x16_bf16(axh1, h1, c11, 0, 0, 0);
        c00 = __builtin_amdgcn_mfma_f32_32x32x16_bf16(axl0, h0, c00, 0, 0, 0);
        c01 = __builtin_amdgcn_mfma_f32_32x32x16_bf16(axl0, h1, c01, 0, 0, 0);
        c10 = __builtin_amdgcn_mfma_f32_32x32x16_bf16(axl1, h0, c10, 0, 0, 0);
        c11 = __builtin_amdgcn_mfma_f32_32x32x16_bf16(axl1, h1, c11, 0, 0, 0);
        c00 = __builtin_amdgcn_mfma_f32_32x32x16_bf16(axh0, l0, c00, 0, 0, 0);
        c01 = __builtin_amdgcn_mfma_f32_32x32x16_bf16(axh0, l1, c01, 0, 0, 0);
        c10 = __builtin_amdgcn_mfma_f32_32x32x16_bf16(axh1, l0, c10, 0, 0, 0);
        c11 = __builtin_amdgcn_mfma_f32_32x32x16_bf16(axh1, l1, c11, 0, 0, 0);
#pragma unroll
        for (int r = 0; r < 16; ++r) {
            rbest0[r] = fmaxf(rbest0[r], fmaxf(c00[r], c01[r]));  // -> v_max3_f32
            rbest1[r] = fmaxf(rbest1[r], fmaxf(c10[r], c11[r]));
        }
    };

    // ROLLED loop (R9 lesson: full unroll -> ds_read hoisting -> VGPR spill).
    // All operands come from LDS; compiler pipelines ds_reads with counted
    // lgkmcnt waits across the small loop body.
    for (int p = 0; p < TPW; p += 2) {
        compute_pair(LDH(p),     LDL(p),     LDN(p),
                     LDH(p + 1), LDL(p + 1), LDN(p + 1));
    }
#undef LDH
#undef LDL
#undef LDN

    // max over the 32 point-columns (lanes within each half)
#pragma unroll
    for (int r = 0; r < 16; ++r) {
        float v0 = rbest0[r];
        v0 = fmaxf(v0, __shfl_xor(v0, 1, 32));
        v0 = fmaxf(v0, __shfl_xor(v0, 2, 32));
        v0 = fmaxf(v0, __shfl_xor(v0, 4, 32));
        v0 = fmaxf(v0, __shfl_xor(v0, 8, 32));
        v0 = fmaxf(v0, __shfl_xor(v0, 16, 32));
        rbest0[r] = v0;
        float v1 = rbest1[r];
        v1 = fmaxf(v1, __shfl_xor(v1, 1, 32));
        v1 = fmaxf(v1, __shfl_xor(v1, 2, 32));
        v1 = fmaxf(v1, __shfl_xor(v1, 4, 32));
        v1 = fmaxf(v1, __shfl_xor(v1, 8, 32));
        v1 = fmaxf(v1, __shfl_xor(v1, 16, 32));
        rbest1[r] = v1;
    }
    if (n31 == 0) {
        float* pp = part + (size_t)cy * NQ + qbase + 4 * half;
#pragma unroll
        for (int r = 0; r < 16; ++r) pp[(r & 3) + 8 * (r >> 2)] = rbest0[r];
        pp += 32;
#pragma unroll
        for (int r = 0; r < 16; ++r) pp[(r & 3) + 8 * (r >> 2)] = rbest1[r];
    }
}

// ---------------------------------------------------------------------------
// Final: reduce SCH chunks, dist2 = ||x||^2 - 2*best, bump.
// ---------------------------------------------------------------------------
__global__ __launch_bounds__(256) void knn_final(const float* __restrict__ x,
                                                 const float* __restrict__ part,
                                                 float* __restrict__ out) {
    const int q = blockIdx.x * 256 + threadIdx.x;
    const float4* xr = (const float4*)(x + (size_t)q * D);
    float4 a = xr[0], b = xr[1], c = xr[2], e = xr[3];
    float x2 = a.x * a.x;
    x2 = fmaf(a.y, a.y, x2); x2 = fmaf(a.z, a.z, x2); x2 = fmaf(a.w, a.w, x2);
    x2 = fmaf(b.x, b.x, x2); x2 = fmaf(b.y, b.y, x2); x2 = fmaf(b.z, b.z, x2); x2 = fmaf(b.w, b.w, x2);
    x2 = fmaf(c.x, c.x, x2); x2 = fmaf(c.y, c.y, x2); x2 = fmaf(c.z, c.z, x2); x2 = fmaf(c.w, c.w, x2);
    x2 = fmaf(e.x, e.x, x2); x2 = fmaf(e.y, e.y, x2); x2 = fmaf(e.z, e.z, x2); x2 = fmaf(e.w, e.w, x2);

    float mbest = -FLT_MAX;
#pragma unroll
    for (int cI = 0; cI < SCH; ++cI) mbest = fmaxf(mbest, part[(size_t)cI * NQ + q]);

    float nn2  = fmaxf(fmaf(-2.f, mbest, x2), 0.f);
    float dist = sqrtf(fmaxf(nn2, 1e-12f));
    float bump = 0.f;
    if (dist < 2.0f) {                      // RADIUS = 2
        float denom = dist * dist - 4.0f;   // d^2 - r^2
        bump = expf(1.0f / denom + 0.25f);  // DECAY/denom + DECAY/r^2
    }
    out[q] = bump;
}

// ===========================================================================
// Fallback (fp32 scalar-pipe path) if workspace is too small for MFMA path.
// ===========================================================================
__global__ __launch_bounds__(256) void neg_half_norms(const float* __restrict__ data,
                                                      float* __restrict__ nhn) {
    const int p = blockIdx.x * 256 + threadIdx.x;
    const float4* r = (const float4*)(data + (size_t)p * D);
    float4 a = r[0], b = r[1], c = r[2], e = r[3];
    float n = a.x * a.x;
    n = fmaf(a.y, a.y, n); n = fmaf(a.z, a.z, n); n = fmaf(a.w, a.w, n);
    n = fmaf(b.x, b.x, n); n = fmaf(b.y, b.y, n); n = fmaf(b.z, b.z, n); n = fmaf(b.w, b.w, n);
    n = fmaf(c.x, c.x, n); n = fmaf(c.y, c.y, n); n = fmaf(c.z, c.z, n); n = fmaf(c.w, c.w, n);
    n = fmaf(e.x, e.x, n); n = fmaf(e.y, e.y, n); n = fmaf(e.z, e.z, n); n = fmaf(e.w, e.w, n);
    nhn[p] = -0.5f * n;
}

__global__ __launch_bounds__(256) void knn_partial_fb(const float* __restrict__ x,
                                                      const float* __restrict__ data,
                                                      const float* __restrict__ nhn,
                                                      float* __restrict__ part, int cp) {
    const int q     = blockIdx.x * 256 + threadIdx.x;
    const int pbase = blockIdx.y * cp;
    const float4* xr = (const float4*)(x + (size_t)q * D);
    const float4 xa = xr[0], xb = xr[1], xc = xr[2], xd = xr[3];
    const float* dp = data + (size_t)pbase * D;
    const float* np = nhn + pbase;
    float best = -FLT_MAX;
    for (int i = 0; i < cp; i += 4) {
#pragma unroll
        for (int j = 0; j < 4; ++j) {
            const float* r  = dp + (size_t)(i + j) * D;
            const float  hn = np[i + j];
            float ca = xa.x * r[0];
            ca = fmaf(xa.y, r[1], ca);  ca = fmaf(xa.z, r[2], ca);  ca = fmaf(xa.w, r[3], ca);
            ca = fmaf(xb.x, r[4], ca);  ca = fmaf(xb.y, r[5], ca);  ca = fmaf(xb.z, r[6], ca);
            ca = fmaf(xb.w, r[7], ca);
            float cb = fmaf(xc.x, r[8], hn);
            cb = fmaf(xc.y, r[9],  cb); cb = fmaf(xc.z, r[10], cb); cb = fmaf(xc.w, r[11], cb);
            cb = fmaf(xd.x, r[12], cb); cb = fmaf(xd.y, r[13], cb); cb = fmaf(xd.z, r[14], cb);
            cb = fmaf(xd.w, r[15], cb);
            best = fmaxf(best, ca + cb);
        }
    }
    part[(size_t)blockIdx.y * NQ + q] = best;
}

__global__ __launch_bounds__(256) void knn_final_fb(const float* __restrict__ x,
                                                    const float* __restrict__ part,
                                                    float* __restrict__ out, int S) {
    const int q = blockIdx.x * 256 + threadIdx.x;
    const float4* xr = (const float4*)(x + (size_t)q * D);
    float4 a = xr[0], b = xr[1], c = xr[2], e = xr[3];
    float x2 = a.x * a.x;
    x2 = fmaf(a.y, a.y, x2); x2 = fmaf(a.z, a.z, x2); x2 = fmaf(a.w, a.w, x2);
    x2 = fmaf(b.x, b.x, x2); x2 = fmaf(b.y, b.y, x2); x2 = fmaf(b.z, b.z, x2); x2 = fmaf(b.w, b.w, x2);
    x2 = fmaf(c.x, c.x, x2); x2 = fmaf(c.y, c.y, x2); x2 = fmaf(c.z, c.z, x2); x2 = fmaf(c.w, c.w, x2);
    x2 = fmaf(e.x, e.x, x2); x2 = fmaf(e.y, e.y, x2); x2 = fmaf(e.z, e.z, x2); x2 = fmaf(e.w, e.w, x2);
    float mb = -FLT_MAX;
    for (int cI = 0; cI < S; ++cI) mb = fmaxf(mb, part[(size_t)cI * NQ + q]);
    float nn2  = fmaxf(fmaf(-2.f, mb, x2), 0.f);
    float dist = sqrtf(fmaxf(nn2, 1e-12f));
    float bump = 0.f;
    if (dist < 2.0f) {
        float denom = dist * dist - 4.0f;
        bump = expf(1.0f / denom + 0.25f);
    }
    out[q] = bump;
}

extern "C" void kernel_launch(void* const* d_in, const int* in_sizes, int n_in,
                              void* d_out, int out_size, void* d_ws, size_t ws_size,
                              hipStream_t stream) {
    const float* x    = (const float*)d_in[0];   // [2048,16] fp32
    const float* data = (const float*)d_in[1];   // [65536,16] fp32
    float* out = (float*)d_out;                  // [2048] fp32

    // ws layout (bytes):
    //   Ppk  [0, 4 MiB)          ND/32 tiles * 1024 shorts (fragment-major)
    //   nhf  [4 MiB, +256 KiB)   ND fp32
    //   part [+512 KiB)          SCH*NQ fp32
    const size_t off_nhf  = (size_t)ND * 32 * 2;             // 4194304
    const size_t off_part = off_nhf + (size_t)ND * 4;        // 4456448
    const size_t needed   = off_part + (size_t)SCH * NQ * 4; // 4980736

    if (ws_size >= needed) {
        unsigned short* Ppk = (unsigned short*)d_ws;
        float* nhf  = (float*)((char*)d_ws + off_nhf);
        float* part = (float*)((char*)d_ws + off_part);

        pack_data<<<ND / 256, 256, 0, stream>>>(data, Ppk, nhf);
        knn_mfma<<<8 * SCH, 256, LDS_BYTES, stream>>>(x, Ppk, nhf, part);
        knn_final<<<NQ / 256, 256, 0, stream>>>(x, part, out);
    } else {
        int S = 32;
        while (S > 1 && (size_t)(ND + S * NQ) * sizeof(float) > ws_size) S >>= 1;
        const int cp = ND / S;
        float* nhn  = (float*)d_ws;
        float* part = (float*)d_ws + ND;
        neg_half_norms<<<ND / 256, 256, 0, stream>>>(data, nhn);
        knn_partial_fb<<<dim3(NQ / 256, S), 256, 0, stream>>>(x, data, nhn, part, cp);
        knn_final_fb<<<NQ / 256, 256, 0, stream>>>(x, part, out, S);
    }
}

// Round 12
// 73.951 us; speedup vs baseline: 1.2661x; 1.0392x over previous
//
#include <hip/hip_runtime.h>
#include <float.h>
#include <math.h>

// Problem constants (fixed by reference setup_inputs)
constexpr int NQ = 2048;    // queries
constexpr int ND = 65536;   // data points
constexpr int D  = 16;      // dims

// ---- MFMA-path tiling (R4/R8/R11 config: best measured) ----
constexpr int SCH   = 64;           // point chunks
constexpr int CP    = ND / SCH;     // 1024 points per chunk
constexpr int TPW   = CP / 32;      // 32 point-tiles (32 pts) per wave

// Dynamic LDS: 64 KiB fragment-major chunk + 4 KiB norms (CP floats).
constexpr unsigned LDS_BYTES = 65536 + 4096;

typedef short bf16x8 __attribute__((ext_vector_type(8)));
typedef float f32x16 __attribute__((ext_vector_type(16)));

__device__ __forceinline__ unsigned short f2bf(float f) {  // RNE fp32->bf16
    unsigned u = __float_as_uint(f);
    u += 0x7FFFu + ((u >> 16) & 1u);
    return (unsigned short)(u >> 16);
}
__device__ __forceinline__ float bf2f(unsigned short h) {
    return __uint_as_float(((unsigned)h) << 16);
}

// ---------------------------------------------------------------------------
// Main kernel (ROUND 12: pack FUSED in — 2-kernel pipeline).
// Per wave: 64 queries (2 q-sets of 32) x one 1024-point chunk.
//   best[q] = max_p ( x_q . p - 0.5*||p||^2 )   (argmin dist2 == argmax this)
// Structural change vs R11: the former pack_data kernel is gone. Each block
// reads its RAW fp32 chunk (64 KiB — same byte count as the packed read!)
// straight from `data`, does the bf16 hi/lo split + norm computation during
// LDS staging, and writes the IDENTICAL fragment-major layout into LDS:
//   tile t (2048 B): [hi h0: cc*8][hi h1: 256+cc*8][lo h0: 512+][lo h1: 768+]
// This deletes: one kernel launch + its graph gap, the 4 MiB Ppk write/read
// round-trip, and the pack->mfma serial dependency. Conversion is replicated
// 8x (per q-slice block) but costs only ~0.5 us/block VALU. All arithmetic
// (f2bf, fmaf order, MFMA sequence) is bit-identical to R11.
// Session ledger baked into this structure:
//   - fragment-major LDS layout -> conflict-free lane-contiguous ds_read_b128
//   - XCD swizzle: all 8 q-slice blocks of chunk cy on XCD cy%8 (R4, -2.4us)
//   - block-level LDS staging of the shared chunk (R8, -4us)
//   - norms in LDS, runtime-indexed (addressed memory, not registers; R11)
//   - loop ROLLED (R9: full unroll -> ds_read hoisting -> VGPR spill)
//   - __launch_bounds__(256,2) NOT (256,4) (R5: min-waves=4 -> 64-VGPR spill)
// LDS = 69632 B dynamic; 2 blocks/CU (139/160 KiB).
// Per 32-pt tile per q-set: 3x mfma_f32_32x32x16_bf16 (hi*hi + lo*hi +
// hi*lo), C seeded with -0.5*||p||^2; 4 independent accumulator chains;
// per-pair epilogue 16x v_max3_f32 per q-set.
// C/D: col = lane&31, row = (reg&3) + 8*(reg>>2) + 4*(lane>>5)  [m74/m101].
// ---------------------------------------------------------------------------
__global__ __launch_bounds__(256, 2) void knn_mfma(const float* __restrict__ x,
                                                   const float* __restrict__ data,
                                                   float* __restrict__ part) {
    // lb = (cy%8) + 8*(qx + 8*(cy/8));  bijective over 512 blocks.
    const int lb  = blockIdx.x;
    const int xcd = lb & 7;
    const int rr  = lb >> 3;       // [0,64)
    const int qx  = rr & 7;        // q-slice [0,8)
    const int cg  = rr >> 3;       // [0,8)
    const int cy  = xcd + 8 * cg;  // chunk [0,64)

    const int tid  = threadIdx.x;
    const int w    = tid >> 6;
    const int l    = tid & 63;
    const int half = l >> 5;
    const int n31  = l & 31;
    const int qbase = qx * 256 + w * 64;   // 4 waves x 64 queries
    const int pbase = cy * CP;

    extern __shared__ __align__(16) char smem[];
    unsigned short* sP = (unsigned short*)smem;          // 64 KiB chunk
    float*          sN = (float*)(smem + 65536);         // 4 KiB: CP norms

    // ---- fused pack: raw fp32 chunk -> bf16 hi/lo fragments + norms in LDS.
    // 4 rounds, one point per thread per round (p_local = j*256 + tid).
    // Identical arithmetic + layout to the former pack_data kernel.
#pragma unroll
    for (int j = 0; j < 4; ++j) {
        const int pl = j * 256 + tid;          // point within chunk [0,1024)
        const float4* r4 = (const float4*)(data + (size_t)(pbase + pl) * D);
        float4 a = r4[0], b = r4[1], c = r4[2], e = r4[3];
        float v[16] = {a.x, a.y, a.z, a.w, b.x, b.y, b.z, b.w,
                       c.x, c.y, c.z, c.w, e.x, e.y, e.z, e.w};
        unsigned short hi[16], lo[16];
        float n = 0.f;
#pragma unroll
        for (int k = 0; k < 16; ++k) {
            n = fmaf(v[k], v[k], n);
            unsigned short h = f2bf(v[k]);
            hi[k] = h;
            lo[k] = f2bf(v[k] - bf2f(h));   // exact residual, rounded to bf16
        }
        const int t  = pl >> 5;               // tile within chunk [0,32)
        const int cc = pl & 31;               // point-in-tile == column
        unsigned short* tb = sP + t * 1024;
        const uint4* h4 = (const uint4*)hi;
        const uint4* l4 = (const uint4*)lo;
        *(uint4*)(tb +       cc * 8) = h4[0];   // hi, half 0 lane (cc)
        *(uint4*)(tb + 256 + cc * 8) = h4[1];   // hi, half 1 lane (32+cc)
        *(uint4*)(tb + 512 + cc * 8) = l4[0];   // lo, half 0
        *(uint4*)(tb + 768 + cc * 8) = l4[1];   // lo, half 1
        sN[pl] = -0.5f * n;
    }

    // ---- A fragments (hi/lo bf16) for both q-sets ----
    bf16x8 axh0, axl0, axh1, axl1;
    {
        const float* xr0 = x + (size_t)(qbase + n31) * D + half * 8;
        float4 a0 = *(const float4*)xr0;
        float4 a1 = *(const float4*)(xr0 + 4);
        const float xv0[8] = {a0.x, a0.y, a0.z, a0.w, a1.x, a1.y, a1.z, a1.w};
#pragma unroll
        for (int k = 0; k < 8; ++k) {
            unsigned short h = f2bf(xv0[k]);
            axh0[k] = (short)h;
            axl0[k] = (short)f2bf(xv0[k] - bf2f(h));
        }
        const float* xr1 = x + (size_t)(qbase + 32 + n31) * D + half * 8;
        float4 b0 = *(const float4*)xr1;
        float4 b1 = *(const float4*)(xr1 + 4);
        const float xv1[8] = {b0.x, b0.y, b0.z, b0.w, b1.x, b1.y, b1.z, b1.w};
#pragma unroll
        for (int k = 0; k < 8; ++k) {
            unsigned short h = f2bf(xv1[k]);
            axh1[k] = (short)h;
            axl1[k] = (short)f2bf(xv1[k] - bf2f(h));
        }
    }

    __syncthreads();   // staging/pack writes visible to all waves

    // LDS read pointers: fragment-major layout (same as packed global was).
    const unsigned short* lp  = sP + l * 8;
    const float*          lnp = sN + n31;
#define LDH(t) (*(const bf16x8*)(lp + (size_t)(t) * 1024))
#define LDL(t) (*(const bf16x8*)(lp + (size_t)(t) * 1024 + 512))
#define LDN(t) (lnp[(t) * 32])

    f32x16 rbest0, rbest1;
#pragma unroll
    for (int r = 0; r < 16; ++r) { rbest0[r] = -FLT_MAX; rbest1[r] = -FLT_MAX; }

    auto compute_pair = [&](bf16x8 h0, bf16x8 l0, float n0,
                            bf16x8 h1, bf16x8 l1, float n1) {
        f32x16 c00, c01, c10, c11;   // c[qset][tile]
#pragma unroll
        for (int r = 0; r < 16; ++r) {
            c00[r] = n0; c01[r] = n1; c10[r] = n0; c11[r] = n1;
        }
        // 4 independent accumulator chains, 3 MFMAs deep each.
        c00 = __builtin_amdgcn_mfma_f32_32x32x16_bf16(axh0, h0, c00, 0, 0, 0);
        c01 = __builtin_amdgcn_mfma_f32_32x32x16_bf16(axh0, h1, c01, 0, 0, 0);
        c10 = __builtin_amdgcn_mfma_f32_32x32x16_bf16(axh1, h0, c10, 0, 0, 0);
        c11 = __builtin_amdgcn_mfma_f32_32x32x16_bf16(axh1, h1, c11, 0, 0, 0);
        c00 = __builtin_amdgcn_mfma_f32_32x32x16_bf16(axl0, h0, c00, 0, 0, 0);
        c01 = __builtin_amdgcn_mfma_f32_32x32x16_bf16(axl0, h1, c01, 0, 0, 0);
        c10 = __builtin_amdgcn_mfma_f32_32x32x16_bf16(axl1, h0, c10, 0, 0, 0);
        c11 = __builtin_amdgcn_mfma_f32_32x32x16_bf16(axl1, h1, c11, 0, 0, 0);
        c00 = __builtin_amdgcn_mfma_f32_32x32x16_bf16(axh0, l0, c00, 0, 0, 0);
        c01 = __builtin_amdgcn_mfma_f32_32x32x16_bf16(axh0, l1, c01, 0, 0, 0);
        c10 = __builtin_amdgcn_mfma_f32_32x32x16_bf16(axh1, l0, c10, 0, 0, 0);
        c11 = __builtin_amdgcn_mfma_f32_32x32x16_bf16(axh1, l1, c11, 0, 0, 0);
#pragma unroll
        for (int r = 0; r < 16; ++r) {
            rbest0[r] = fmaxf(rbest0[r], fmaxf(c00[r], c01[r]));  // -> v_max3_f32
            rbest1[r] = fmaxf(rbest1[r], fmaxf(c10[r], c11[r]));
        }
    };

    // ROLLED loop (R9 lesson: full unroll -> ds_read hoisting -> VGPR spill).
    for (int p = 0; p < TPW; p += 2) {
        compute_pair(LDH(p),     LDL(p),     LDN(p),
                     LDH(p + 1), LDL(p + 1), LDN(p + 1));
    }
#undef LDH
#undef LDL
#undef LDN

    // max over the 32 point-columns (lanes within each half)
#pragma unroll
    for (int r = 0; r < 16; ++r) {
        float v0 = rbest0[r];
        v0 = fmaxf(v0, __shfl_xor(v0, 1, 32));
        v0 = fmaxf(v0, __shfl_xor(v0, 2, 32));
        v0 = fmaxf(v0, __shfl_xor(v0, 4, 32));
        v0 = fmaxf(v0, __shfl_xor(v0, 8, 32));
        v0 = fmaxf(v0, __shfl_xor(v0, 16, 32));
        rbest0[r] = v0;
        float v1 = rbest1[r];
        v1 = fmaxf(v1, __shfl_xor(v1, 1, 32));
        v1 = fmaxf(v1, __shfl_xor(v1, 2, 32));
        v1 = fmaxf(v1, __shfl_xor(v1, 4, 32));
        v1 = fmaxf(v1, __shfl_xor(v1, 8, 32));
        v1 = fmaxf(v1, __shfl_xor(v1, 16, 32));
        rbest1[r] = v1;
    }
    if (n31 == 0) {
        float* pp = part + (size_t)cy * NQ + qbase + 4 * half;
#pragma unroll
        for (int r = 0; r < 16; ++r) pp[(r & 3) + 8 * (r >> 2)] = rbest0[r];
        pp += 32;
#pragma unroll
        for (int r = 0; r < 16; ++r) pp[(r & 3) + 8 * (r >> 2)] = rbest1[r];
    }
}

// ---------------------------------------------------------------------------
// Final: reduce SCH chunks, dist2 = ||x||^2 - 2*best, bump.
// ---------------------------------------------------------------------------
__global__ __launch_bounds__(256) void knn_final(const float* __restrict__ x,
                                                 const float* __restrict__ part,
                                                 float* __restrict__ out) {
    const int q = blockIdx.x * 256 + threadIdx.x;
    const float4* xr = (const float4*)(x + (size_t)q * D);
    float4 a = xr[0], b = xr[1], c = xr[2], e = xr[3];
    float x2 = a.x * a.x;
    x2 = fmaf(a.y, a.y, x2); x2 = fmaf(a.z, a.z, x2); x2 = fmaf(a.w, a.w, x2);
    x2 = fmaf(b.x, b.x, x2); x2 = fmaf(b.y, b.y, x2); x2 = fmaf(b.z, b.z, x2); x2 = fmaf(b.w, b.w, x2);
    x2 = fmaf(c.x, c.x, x2); x2 = fmaf(c.y, c.y, x2); x2 = fmaf(c.z, c.z, x2); x2 = fmaf(c.w, c.w, x2);
    x2 = fmaf(e.x, e.x, x2); x2 = fmaf(e.y, e.y, x2); x2 = fmaf(e.z, e.z, x2); x2 = fmaf(e.w, e.w, x2);

    float mbest = -FLT_MAX;
#pragma unroll
    for (int cI = 0; cI < SCH; ++cI) mbest = fmaxf(mbest, part[(size_t)cI * NQ + q]);

    float nn2  = fmaxf(fmaf(-2.f, mbest, x2), 0.f);
    float dist = sqrtf(fmaxf(nn2, 1e-12f));
    float bump = 0.f;
    if (dist < 2.0f) {                      // RADIUS = 2
        float denom = dist * dist - 4.0f;   // d^2 - r^2
        bump = expf(1.0f / denom + 0.25f);  // DECAY/denom + DECAY/r^2
    }
    out[q] = bump;
}

// ===========================================================================
// Fallback (fp32 scalar-pipe path) if workspace is too small for MFMA path.
// ===========================================================================
__global__ __launch_bounds__(256) void neg_half_norms(const float* __restrict__ data,
                                                      float* __restrict__ nhn) {
    const int p = blockIdx.x * 256 + threadIdx.x;
    const float4* r = (const float4*)(data + (size_t)p * D);
    float4 a = r[0], b = r[1], c = r[2], e = r[3];
    float n = a.x * a.x;
    n = fmaf(a.y, a.y, n); n = fmaf(a.z, a.z, n); n = fmaf(a.w, a.w, n);
    n = fmaf(b.x, b.x, n); n = fmaf(b.y, b.y, n); n = fmaf(b.z, b.z, n); n = fmaf(b.w, b.w, n);
    n = fmaf(c.x, c.x, n); n = fmaf(c.y, c.y, n); n = fmaf(c.z, c.z, n); n = fmaf(c.w, c.w, n);
    n = fmaf(e.x, e.x, n); n = fmaf(e.y, e.y, n); n = fmaf(e.z, e.z, n); n = fmaf(e.w, e.w, n);
    nhn[p] = -0.5f * n;
}

__global__ __launch_bounds__(256) void knn_partial_fb(const float* __restrict__ x,
                                                      const float* __restrict__ data,
                                                      const float* __restrict__ nhn,
                                                      float* __restrict__ part, int cp) {
    const int q     = blockIdx.x * 256 + threadIdx.x;
    const int pbase = blockIdx.y * cp;
    const float4* xr = (const float4*)(x + (size_t)q * D);
    const float4 xa = xr[0], xb = xr[1], xc = xr[2], xd = xr[3];
    const float* dp = data + (size_t)pbase * D;
    const float* np = nhn + pbase;
    float best = -FLT_MAX;
    for (int i = 0; i < cp; i += 4) {
#pragma unroll
        for (int j = 0; j < 4; ++j) {
            const float* r  = dp + (size_t)(i + j) * D;
            const float  hn = np[i + j];
            float ca = xa.x * r[0];
            ca = fmaf(xa.y, r[1], ca);  ca = fmaf(xa.z, r[2], ca);  ca = fmaf(xa.w, r[3], ca);
            ca = fmaf(xb.x, r[4], ca);  ca = fmaf(xb.y, r[5], ca);  ca = fmaf(xb.z, r[6], ca);
            ca = fmaf(xb.w, r[7], ca);
            float cb = fmaf(xc.x, r[8], hn);
            cb = fmaf(xc.y, r[9],  cb); cb = fmaf(xc.z, r[10], cb); cb = fmaf(xc.w, r[11], cb);
            cb = fmaf(xd.x, r[12], cb); cb = fmaf(xd.y, r[13], cb); cb = fmaf(xd.z, r[14], cb);
            cb = fmaf(xd.w, r[15], cb);
            best = fmaxf(best, ca + cb);
        }
    }
    part[(size_t)blockIdx.y * NQ + q] = best;
}

__global__ __launch_bounds__(256) void knn_final_fb(const float* __restrict__ x,
                                                    const float* __restrict__ part,
                                                    float* __restrict__ out, int S) {
    const int q = blockIdx.x * 256 + threadIdx.x;
    const float4* xr = (const float4*)(x + (size_t)q * D);
    float4 a = xr[0], b = xr[1], c = xr[2], e = xr[3];
    float x2 = a.x * a.x;
    x2 = fmaf(a.y, a.y, x2); x2 = fmaf(a.z, a.z, x2); x2 = fmaf(a.w, a.w, x2);
    x2 = fmaf(b.x, b.x, x2); x2 = fmaf(b.y, b.y, x2); x2 = fmaf(b.z, b.z, x2); x2 = fmaf(b.w, b.w, x2);
    x2 = fmaf(c.x, c.x, x2); x2 = fmaf(c.y, c.y, x2); x2 = fmaf(c.z, c.z, x2); x2 = fmaf(c.w, c.w, x2);
    x2 = fmaf(e.x, e.x, x2); x2 = fmaf(e.y, e.y, x2); x2 = fmaf(e.z, e.z, x2); x2 = fmaf(e.w, e.w, x2);
    float mb = -FLT_MAX;
    for (int cI = 0; cI < S; ++cI) mb = fmaxf(mb, part[(size_t)cI * NQ + q]);
    float nn2  = fmaxf(fmaf(-2.f, mb, x2), 0.f);
    float dist = sqrtf(fmaxf(nn2, 1e-12f));
    float bump = 0.f;
    if (dist < 2.0f) {
        float denom = dist * dist - 4.0f;
        bump = expf(1.0f / denom + 0.25f);
    }
    out[q] = bump;
}

extern "C" void kernel_launch(void* const* d_in, const int* in_sizes, int n_in,
                              void* d_out, int out_size, void* d_ws, size_t ws_size,
                              hipStream_t stream) {
    const float* x    = (const float*)d_in[0];   // [2048,16] fp32
    const float* data = (const float*)d_in[1];   // [65536,16] fp32
    float* out = (float*)d_out;                  // [2048] fp32

    // ws layout (bytes): part only — SCH*NQ fp32 = 512 KiB.
    const size_t needed = (size_t)SCH * NQ * 4;  // 524288

    if (ws_size >= needed) {
        float* part = (float*)d_ws;
        knn_mfma<<<8 * SCH, 256, LDS_BYTES, stream>>>(x, data, part);
        knn_final<<<NQ / 256, 256, 0, stream>>>(x, part, out);
    } else {
        int S = 32;
        while (S > 1 && (size_t)(ND + S * NQ) * sizeof(float) > ws_size) S >>= 1;
        const int cp = ND / S;
        float* nhn  = (float*)d_ws;
        float* part = (float*)d_ws + ND;
        neg_half_norms<<<ND / 256, 256, 0, stream>>>(data, nhn);
        knn_partial_fb<<<dim3(NQ / 256, S), 256, 0, stream>>>(x, data, nhn, part, cp);
        knn_final_fb<<<NQ / 256, 256, 0, stream>>>(x, part, out, S);
    }
}